// Round 19
// baseline (65.332 us; speedup 1.0000x reference)
//
#include <hip/hip_runtime.h>
#include <hip/hip_bf16.h>
#include <math.h>

// Shapes
#define QL 32768
#define DD 1024
#define NTOK 64

using short8   = __attribute__((ext_vector_type(8))) short;
using f32x4    = __attribute__((ext_vector_type(4))) float;
using float4v  = __attribute__((ext_vector_type(4))) float;
using ushort4v = __attribute__((ext_vector_type(4))) unsigned short;

// RNE f32->bf16 via bit trick (exact RNE)
__device__ __forceinline__ unsigned short f2bf(float f) {
    unsigned int u = __float_as_uint(f);
    unsigned int r = (u + 0x7FFFu + ((u >> 16) & 1u)) >> 16;
    return (unsigned short)r;
}

__device__ __forceinline__ short8 pack_bf16x8(float4v lo, float4v hi) {
    short8 a;
    ((__hip_bfloat162*)&a)[0] = __float22bfloat162_rn(float2{lo.x, lo.y});
    ((__hip_bfloat162*)&a)[1] = __float22bfloat162_rn(float2{lo.z, lo.w});
    ((__hip_bfloat162*)&a)[2] = __float22bfloat162_rn(float2{hi.x, hi.y});
    ((__hip_bfloat162*)&a)[3] = __float22bfloat162_rn(float2{hi.z, hi.w});
    return a;
}

// async global->LDS, 16B per lane; dest = wave-uniform base + lane*16
__device__ __forceinline__ void gload_lds16(const void* g, void* l) {
    __builtin_amdgcn_global_load_lds(
        (const __attribute__((address_space(1))) void*)g,
        (__attribute__((address_space(3))) void*)l,
        16, 0, 0);
}

// ---------------------------------------------------------------------------
// Merged prologue (verified r18): ONE launch, grid 80 x 256.
// Blocks 0..63: Kp[:, b*16..b*16+16] = Pk @ Wq via LDS-transposed Wq stripe.
// Blocks 64..79: PvT[e][t] = bf16(Pv[t][e]).
// ---------------------------------------------------------------------------
#define WQT_STRIDE 1048   // elements; 2096 B per e-row, 16B aligned
__global__ __launch_bounds__(256) void kpv_kernel(
        const float* __restrict__ Wq, const float* __restrict__ Pk,
        const float* __restrict__ Pv,
        unsigned short* __restrict__ Kp, unsigned short* __restrict__ PvT) {
    __shared__ __align__(16) unsigned char sm[16 * WQT_STRIDE * 2];  // 33536 B
    const int tid = threadIdx.x;

    if (blockIdx.x < 64) {
        const int N0 = blockIdx.x * 16;
        unsigned short* wqt = (unsigned short*)sm;   // [16 e][WQT_STRIDE d]

        const int c4 = (tid & 3) * 4;
#pragma unroll
        for (int p = 0; p < 16; ++p) {
            const int row = p * 64 + (tid >> 2);     // d index 0..1023
            const float4v v = *(const float4v*)(Wq + (size_t)row * DD + N0 + c4);
#pragma unroll
            for (int k = 0; k < 4; ++k)
                wqt[(size_t)(c4 + k) * WQT_STRIDE + row] = f2bf(v[k]);
        }
        __syncthreads();

        const int w   = tid >> 6;
        const int l   = tid & 63;
        const int lhi = l >> 4;
        const int llo = l & 15;

        f32x4 acc = (f32x4){0.f, 0.f, 0.f, 0.f};
        for (int kb = 0; kb < 32; ++kb) {
            const int k0 = kb * 32 + lhi * 8;
            float4v p0 = *(const float4v*)(Pk + (size_t)(w * 16 + llo) * DD + k0);
            float4v p1 = *(const float4v*)(Pk + (size_t)(w * 16 + llo) * DD + k0 + 4);
            short8 a = pack_bf16x8(p0, p1);
            short8 b = *(const short8*)(wqt + (size_t)llo * WQT_STRIDE + k0);
            acc = __builtin_amdgcn_mfma_f32_16x16x32_bf16(a, b, acc, 0, 0, 0);
        }
#pragma unroll
        for (int j = 0; j < 4; ++j) {
            const int t = w * 16 + lhi * 4 + j;
            Kp[(size_t)t * DD + N0 + llo] = f2bf(acc[j]);
        }
    } else {
        float (*tile)[65] = (float (*)[65])(void*)sm;    // 16640 B <= 33536
        const int c0 = (blockIdx.x - 64) * 64;
#pragma unroll
        for (int i = 0; i < 16; ++i) {
            const int lin = tid + 256 * i;
            const int row = lin >> 6, col = lin & 63;
            tile[row][col] = Pv[(size_t)row * DD + c0 + col];
        }
        __syncthreads();
#pragma unroll
        for (int i = 0; i < 16; ++i) {
            const int lin = tid + 256 * i;
            const int row = lin >> 6, col = lin & 63;
            PvT[(size_t)(c0 + row) * 64 + col] = f2bf(tile[col][row]);
        }
    }
}

// ---------------------------------------------------------------------------
// Fused main (r18 structure; B-operand moved from LDS-staging to VGPRs):
// grid 256 x 512 (8 waves), 128 q-rows/block (1 block/CU).
// B preload: lane's entire Kp row (token wt*16+llo, 1024 k) -> 32 short8
//   frags (128 VGPR), loaded once before the pipeline.
// Phase A: 16 K-steps of 64. 3-deep circular A-bufs (x fp32, 32 KB/step),
//   global_load_lds, 4 ops/thread/step; counted s_waitcnt vmcnt(4) + raw
//   s_barrier per step. Swizzle rule #21 as verified.
// Phase B: s -> sSf[128][68] (alias A-bufs) -> 4-lane shfl norm*8 -> exact
//   GELU -> s' bf16 [128][128B] swizzled at smem+65536.
// Phase C: y = s' @ Pv swapped MFMA (D[m=d][n=q]); PvT frags from L2;
//   float4 stores. Wave w owns d-cols w*128..+128. (r18 verbatim)
// ---------------------------------------------------------------------------
__global__ __launch_bounds__(512) void pattn_kernel(
        const float* __restrict__ x, const unsigned short* __restrict__ Kp,
        const unsigned short* __restrict__ PvT, float* __restrict__ out) {
    __shared__ __align__(16) unsigned char smem[98304];   // 3 x 32K A-bufs

    const int tid = threadIdx.x;
    const int w   = tid >> 6;     // 0..7
    const int l   = tid & 63;
    const int lhi = l >> 4;       // 0..3
    const int llo = l & 15;       // 0..15
    const int wr  = w >> 2;       // 0..1  row-half
    const int wt  = w & 3;        // 0..3  token-slice
    const int R0  = blockIdx.x * 128;
    const char* xb = (const char*)x;

    // ---- B preload: 32 short8 frags = lane's full Kp row (2 KB) ----
    // frag i (= t*2+ks) covers k = i*32 + lhi*8 .. +8 of row wt*16+llo.
    short8 bR[32];
    {
        const unsigned short* kprow = Kp + (size_t)(wt * 16 + llo) * DD + lhi * 8;
#pragma unroll
        for (int i = 0; i < 32; ++i)
            bR[i] = *(const short8*)(kprow + i * 32);
    }

    f32x4 acc[4];
#pragma unroll
    for (int rf = 0; rf < 4; ++rf) acc[rf] = (f32x4){0.f, 0.f, 0.f, 0.f};

#define ABUF(t) (smem + ((t) % 3) * 32768)

#define STAGE(t)                                                                \
    {                                                                           \
        unsigned char* abuf = ABUF(t);                                          \
        _Pragma("unroll")                                                       \
        for (int i = 0; i < 4; ++i) {                                           \
            const int row = i * 32 + w * 4 + (l >> 4);                          \
            const int csw = (l & 15) ^ ((row & 7) << 1);                        \
            gload_lds16(xb + (size_t)(R0 + row) * 4096 + (t) * 256 + csw * 16,  \
                        (void*)(abuf + (i * 32 + w * 4) * 256));                \
        }                                                                       \
    }

#define COMPUTE(t)                                                              \
    {                                                                           \
        unsigned char* abuf = ABUF(t);                                          \
        _Pragma("unroll")                                                       \
        for (int ks = 0; ks < 2; ++ks) {                                        \
            const short8 bfrg = bR[(t) * 2 + ks];                               \
            _Pragma("unroll")                                                   \
            for (int rf = 0; rf < 4; ++rf) {                                    \
                const int arow  = wr * 64 + rf * 16 + llo;                      \
                const int abyte = arow * 256 +                                  \
                                  (((ks * 4 + lhi) ^ (arow & 7)) << 5);         \
                const float4v f0 = *(const float4v*)(abuf + abyte);             \
                const float4v f1 = *(const float4v*)(abuf + abyte + 16);        \
                short8 a = pack_bf16x8(f0, f1);                                 \
                acc[rf] = __builtin_amdgcn_mfma_f32_16x16x32_bf16(a, bfrg, acc[rf], 0, 0, 0); \
            }                                                                   \
        }                                                                       \
    }

    // ---- Phase A: depth-3 pipeline, 2-step lookahead, counted vmcnt ----
    STAGE(0); STAGE(1);
#pragma unroll
    for (int t = 0; t < 16; ++t) {
        if (t < 15) { asm volatile("s_waitcnt vmcnt(4)" ::: "memory"); }
        else        { asm volatile("s_waitcnt vmcnt(0)" ::: "memory"); }
        __builtin_amdgcn_s_barrier();
        __builtin_amdgcn_sched_barrier(0);
        if (t < 14) STAGE(t + 2);
        COMPUTE(t);
    }
#undef STAGE
#undef COMPUTE
#undef ABUF

    __syncthreads();   // pipeline fully retired -> LDS free for aliases

    // ---- Phase B: s rows -> sSf, 4-lane norm, exact GELU -> s' LDS ----
    float (*sSf)[68] = (float (*)[68])(void*)smem;          // [128][68] f32, 34.8 KB
#pragma unroll
    for (int rf = 0; rf < 4; ++rf)
#pragma unroll
        for (int j = 0; j < 4; ++j)
            sSf[wr * 64 + rf * 16 + lhi * 4 + j][wt * 16 + llo] = acc[rf][j];
    __syncthreads();

    unsigned char* sP = smem + 65536;                       // s' [128][128B] swizzled, 16 KB
    {
        const int r  = tid >> 2;          // 0..127 q-row
        const int tq = tid & 3;           // 16-token slice
        const f32x4 v0 = *(const f32x4*)&sSf[r][tq * 16];
        const f32x4 v1 = *(const f32x4*)&sSf[r][tq * 16 + 4];
        const f32x4 v2 = *(const f32x4*)&sSf[r][tq * 16 + 8];
        const f32x4 v3 = *(const f32x4*)&sSf[r][tq * 16 + 12];
        float ssq = v0.x*v0.x + v0.y*v0.y + v0.z*v0.z + v0.w*v0.w
                  + v1.x*v1.x + v1.y*v1.y + v1.z*v1.z + v1.w*v1.w
                  + v2.x*v2.x + v2.y*v2.y + v2.z*v2.z + v2.w*v2.w
                  + v3.x*v3.x + v3.y*v3.y + v3.z*v3.z + v3.w*v3.w;
        ssq += __shfl_xor(ssq, 1);
        ssq += __shfl_xor(ssq, 2);
        const float scale = 8.0f / sqrtf(ssq);
        short8 g0, g1;
#pragma unroll
        for (int k = 0; k < 4; ++k) {
            const float a0 = v0[k] * scale, a1 = v1[k] * scale;
            const float a2 = v2[k] * scale, a3 = v3[k] * scale;
            g0[k]     = (short)f2bf(0.5f * a0 * (1.0f + erff(a0 * 0.70710678118654752f)));
            g0[4 + k] = (short)f2bf(0.5f * a1 * (1.0f + erff(a1 * 0.70710678118654752f)));
            g1[k]     = (short)f2bf(0.5f * a2 * (1.0f + erff(a2 * 0.70710678118654752f)));
            g1[4 + k] = (short)f2bf(0.5f * a3 * (1.0f + erff(a3 * 0.70710678118654752f)));
        }
        *(short8*)(sP + r * 128 + (((2 * tq)     ^ (r & 7)) << 4)) = g0;
        *(short8*)(sP + r * 128 + (((2 * tq + 1) ^ (r & 7)) << 4)) = g1;
    }
    __syncthreads();

    // ---- Phase C: y = s' @ Pv (swapped: D[m=d][n=q]); float4 stores ----
    short8 sfr[8][2];
#pragma unroll
    for (int qb = 0; qb < 8; ++qb)
#pragma unroll
        for (int ks = 0; ks < 2; ++ks) {
            const int q = qb * 16 + llo;
            sfr[qb][ks] = *(const short8*)(sP + q * 128 +
                              (((ks * 4 + lhi) ^ (q & 7)) << 4));
        }

    const int d0 = w * 128;
#pragma unroll 2
    for (int dt = 0; dt < 8; ++dt) {
        const unsigned short* ap = PvT + (size_t)(d0 + dt * 16 + llo) * 64 + lhi * 8;
        const short8 pa0 = *(const short8*)ap;
        const short8 pa1 = *(const short8*)(ap + 32);
#pragma unroll
        for (int qb = 0; qb < 8; ++qb) {
            f32x4 c2 = (f32x4){0.f, 0.f, 0.f, 0.f};
            c2 = __builtin_amdgcn_mfma_f32_16x16x32_bf16(pa0, sfr[qb][0], c2, 0, 0, 0);
            c2 = __builtin_amdgcn_mfma_f32_16x16x32_bf16(pa1, sfr[qb][1], c2, 0, 0, 0);
            *(float4v*)(out + (size_t)(R0 + qb * 16 + llo) * DD + d0 + dt * 16 + lhi * 4) = c2;
        }
    }
}

// ---------------------------------------------------------------------------
extern "C" void kernel_launch(void* const* d_in, const int* in_sizes, int n_in,
                              void* d_out, int out_size, void* d_ws, size_t ws_size,
                              hipStream_t stream) {
    (void)in_sizes; (void)n_in; (void)out_size; (void)ws_size;
    const float* x  = (const float*)d_in[0];
    const float* Wq = (const float*)d_in[1];
    const float* Pk = (const float*)d_in[2];
    const float* Pv = (const float*)d_in[3];
    float* out = (float*)d_out;

    // ws layout (256 KB): Kp bf16 [64][1024] @ 0; PvT bf16 [1024][64] @ 128K
    unsigned short* Kp  = (unsigned short*)d_ws;
    unsigned short* PvT = (unsigned short*)((char*)d_ws + 131072);

    kpv_kernel<<<80, 256, 0, stream>>>(Wq, Pk, Pv, Kp, PvT);
    pattn_kernel<<<256, 512, 0, stream>>>(x, Kp, PvT, out);
}

// Round 20
// 59.215 us; speedup vs baseline: 1.1033x; 1.1033x over previous
//
#include <hip/hip_runtime.h>
#include <hip/hip_bf16.h>
#include <math.h>

// Shapes
#define QL 32768
#define DD 1024
#define NTOK 64

using short8   = __attribute__((ext_vector_type(8))) short;
using f32x4    = __attribute__((ext_vector_type(4))) float;
using float4v  = __attribute__((ext_vector_type(4))) float;
using ushort4v = __attribute__((ext_vector_type(4))) unsigned short;

// RNE f32->bf16 via bit trick (exact RNE)
__device__ __forceinline__ unsigned short f2bf(float f) {
    unsigned int u = __float_as_uint(f);
    unsigned int r = (u + 0x7FFFu + ((u >> 16) & 1u)) >> 16;
    return (unsigned short)r;
}

__device__ __forceinline__ short8 pack_bf16x8(float4v lo, float4v hi) {
    short8 a;
    ((__hip_bfloat162*)&a)[0] = __float22bfloat162_rn(float2{lo.x, lo.y});
    ((__hip_bfloat162*)&a)[1] = __float22bfloat162_rn(float2{lo.z, lo.w});
    ((__hip_bfloat162*)&a)[2] = __float22bfloat162_rn(float2{hi.x, hi.y});
    ((__hip_bfloat162*)&a)[3] = __float22bfloat162_rn(float2{hi.z, hi.w});
    return a;
}

// async global->LDS, 16B per lane; dest = wave-uniform base + lane*16
__device__ __forceinline__ void gload_lds16(const void* g, void* l) {
    __builtin_amdgcn_global_load_lds(
        (const __attribute__((address_space(1))) void*)g,
        (__attribute__((address_space(3))) void*)l,
        16, 0, 0);
}

// ---------------------------------------------------------------------------
// Merged prologue (verified r18): ONE launch, grid 80 x 256.
// Blocks 0..63: Kp[:, b*16..b*16+16] = Pk @ Wq via LDS-transposed Wq stripe.
// Blocks 64..79: PvT[e][t] = bf16(Pv[t][e]).
// ---------------------------------------------------------------------------
#define WQT_STRIDE 1048   // elements; 2096 B per e-row, 16B aligned
__global__ __launch_bounds__(256) void kpv_kernel(
        const float* __restrict__ Wq, const float* __restrict__ Pk,
        const float* __restrict__ Pv,
        unsigned short* __restrict__ Kp, unsigned short* __restrict__ PvT) {
    __shared__ __align__(16) unsigned char sm[16 * WQT_STRIDE * 2];  // 33536 B
    const int tid = threadIdx.x;

    if (blockIdx.x < 64) {
        const int N0 = blockIdx.x * 16;
        unsigned short* wqt = (unsigned short*)sm;   // [16 e][WQT_STRIDE d]

        const int c4 = (tid & 3) * 4;
#pragma unroll
        for (int p = 0; p < 16; ++p) {
            const int row = p * 64 + (tid >> 2);     // d index 0..1023
            const float4v v = *(const float4v*)(Wq + (size_t)row * DD + N0 + c4);
#pragma unroll
            for (int k = 0; k < 4; ++k)
                wqt[(size_t)(c4 + k) * WQT_STRIDE + row] = f2bf(v[k]);
        }
        __syncthreads();

        const int w   = tid >> 6;
        const int l   = tid & 63;
        const int lhi = l >> 4;
        const int llo = l & 15;

        f32x4 acc = (f32x4){0.f, 0.f, 0.f, 0.f};
        for (int kb = 0; kb < 32; ++kb) {
            const int k0 = kb * 32 + lhi * 8;
            float4v p0 = *(const float4v*)(Pk + (size_t)(w * 16 + llo) * DD + k0);
            float4v p1 = *(const float4v*)(Pk + (size_t)(w * 16 + llo) * DD + k0 + 4);
            short8 a = pack_bf16x8(p0, p1);
            short8 b = *(const short8*)(wqt + (size_t)llo * WQT_STRIDE + k0);
            acc = __builtin_amdgcn_mfma_f32_16x16x32_bf16(a, b, acc, 0, 0, 0);
        }
#pragma unroll
        for (int j = 0; j < 4; ++j) {
            const int t = w * 16 + lhi * 4 + j;
            Kp[(size_t)t * DD + N0 + llo] = f2bf(acc[j]);
        }
    } else {
        float (*tile)[65] = (float (*)[65])(void*)sm;    // 16640 B <= 33536
        const int c0 = (blockIdx.x - 64) * 64;
#pragma unroll
        for (int i = 0; i < 16; ++i) {
            const int lin = tid + 256 * i;
            const int row = lin >> 6, col = lin & 63;
            tile[row][col] = Pv[(size_t)row * DD + c0 + col];
        }
        __syncthreads();
#pragma unroll
        for (int i = 0; i < 16; ++i) {
            const int lin = tid + 256 * i;
            const int row = lin >> 6, col = lin & 63;
            PvT[(size_t)(c0 + row) * 64 + col] = f2bf(tile[col][row]);
        }
    }
}

// ---------------------------------------------------------------------------
// Fused main (r18 verbatim — best measured: 59.3 µs total):
// grid 256 x 512 (8 waves), 128 q-rows/block (1 block/CU).
// Phase A: 16 K-steps of 64. 3-deep circular LDS bufs, global_load_lds for
//   A (x fp32 [128][64], 32 KB/step) and B (Kp bf16 [64][64], 8 KB/step);
//   counted s_waitcnt vmcnt(5) + raw s_barrier per step (T3/T4).
// Phase B: partial s -> sSf[128][68] (alias dead A-bufs) -> 4-lane shfl norm
//   -> exact GELU -> s' bf16 [128][128B] swizzled (alias dead B-bufs).
// Phase C: y = s' @ Pv swapped MFMA (D[m=d][n=q]); s'-frags in 64 VGPR,
//   PvT frags from L2; float4 stores. Wave w owns d-cols w*128..+128.
// ---------------------------------------------------------------------------
__global__ __launch_bounds__(512) void pattn_kernel(
        const float* __restrict__ x, const unsigned short* __restrict__ Kp,
        const unsigned short* __restrict__ PvT, float* __restrict__ out) {
    __shared__ __align__(16) unsigned char smem[122880];   // 3*32K (A) + 3*8K (B)

    const int tid = threadIdx.x;
    const int w   = tid >> 6;     // 0..7
    const int l   = tid & 63;
    const int lhi = l >> 4;       // 0..3
    const int llo = l & 15;       // 0..15
    const int wr  = w >> 2;       // 0..1  row-half
    const int wt  = w & 3;        // 0..3  token-slice
    const int R0  = blockIdx.x * 128;
    const char* xb  = (const char*)x;
    const char* kpb = (const char*)Kp;

    f32x4 acc[4];
#pragma unroll
    for (int rf = 0; rf < 4; ++rf) acc[rf] = (f32x4){0.f, 0.f, 0.f, 0.f};

#define ABUF(t) (smem + ((t) % 3) * 32768)
#define BBUF(t) (smem + 98304 + ((t) % 3) * 8192)

#define STAGE(t)                                                                \
    {                                                                           \
        unsigned char* abuf = ABUF(t);                                          \
        unsigned char* bbuf = BBUF(t);                                          \
        _Pragma("unroll")                                                       \
        for (int i = 0; i < 4; ++i) {                                           \
            const int row = i * 32 + w * 4 + (l >> 4);                          \
            const int csw = (l & 15) ^ ((row & 7) << 1);                        \
            gload_lds16(xb + (size_t)(R0 + row) * 4096 + (t) * 256 + csw * 16,  \
                        (void*)(abuf + (i * 32 + w * 4) * 256));                \
        }                                                                       \
        const int brow = w * 8 + (l >> 3);                                      \
        const int bcs  = (l & 7) ^ (brow & 7);                                  \
        gload_lds16(kpb + (size_t)brow * 2048 + (t) * 128 + bcs * 16,           \
                    (void*)(bbuf + (w * 8) * 128));                             \
    }

#define COMPUTE(t)                                                              \
    {                                                                           \
        unsigned char* abuf = ABUF(t);                                          \
        unsigned char* bbuf = BBUF(t);                                          \
        _Pragma("unroll")                                                       \
        for (int ks = 0; ks < 2; ++ks) {                                        \
            const int btok = wt * 16 + llo;                                     \
            const short8 bfrg = *(const short8*)(bbuf + btok * 128 +            \
                                  (((ks * 4 + lhi) ^ (btok & 7)) << 4));        \
            _Pragma("unroll")                                                   \
            for (int rf = 0; rf < 4; ++rf) {                                    \
                const int arow  = wr * 64 + rf * 16 + llo;                      \
                const int abyte = arow * 256 +                                  \
                                  (((ks * 4 + lhi) ^ (arow & 7)) << 5);         \
                const float4v f0 = *(const float4v*)(abuf + abyte);             \
                const float4v f1 = *(const float4v*)(abuf + abyte + 16);        \
                short8 a = pack_bf16x8(f0, f1);                                 \
                acc[rf] = __builtin_amdgcn_mfma_f32_16x16x32_bf16(a, bfrg, acc[rf], 0, 0, 0); \
            }                                                                   \
        }                                                                       \
    }

    // ---- Phase A: depth-3 pipeline, 2-step lookahead, counted vmcnt ----
    STAGE(0); STAGE(1);
#pragma unroll
    for (int t = 0; t < 16; ++t) {
        if (t < 15) { asm volatile("s_waitcnt vmcnt(5)" ::: "memory"); }
        else        { asm volatile("s_waitcnt vmcnt(0)" ::: "memory"); }
        __builtin_amdgcn_s_barrier();
        __builtin_amdgcn_sched_barrier(0);
        if (t < 14) STAGE(t + 2);
        COMPUTE(t);
    }
#undef STAGE
#undef COMPUTE
#undef ABUF
#undef BBUF

    __syncthreads();   // pipeline fully retired -> LDS free for aliases

    // ---- Phase B: partials -> sSf, 4-lane norm, exact GELU -> s' LDS ----
    float (*sSf)[68] = (float (*)[68])(void*)smem;          // [128][68] f32, 34.8 KB
#pragma unroll
    for (int rf = 0; rf < 4; ++rf)
#pragma unroll
        for (int j = 0; j < 4; ++j)
            sSf[wr * 64 + rf * 16 + lhi * 4 + j][wt * 16 + llo] = acc[rf][j];
    __syncthreads();

    unsigned char* sP = smem + 98304;                       // s' [128][128B] swizzled, 16 KB
    {
        const int r  = tid >> 2;          // 0..127 q-row
        const int tq = tid & 3;           // 16-token slice
        const f32x4 v0 = *(const f32x4*)&sSf[r][tq * 16];
        const f32x4 v1 = *(const f32x4*)&sSf[r][tq * 16 + 4];
        const f32x4 v2 = *(const f32x4*)&sSf[r][tq * 16 + 8];
        const f32x4 v3 = *(const f32x4*)&sSf[r][tq * 16 + 12];
        float ssq = v0.x*v0.x + v0.y*v0.y + v0.z*v0.z + v0.w*v0.w
                  + v1.x*v1.x + v1.y*v1.y + v1.z*v1.z + v1.w*v1.w
                  + v2.x*v2.x + v2.y*v2.y + v2.z*v2.z + v2.w*v2.w
                  + v3.x*v3.x + v3.y*v3.y + v3.z*v3.z + v3.w*v3.w;
        ssq += __shfl_xor(ssq, 1);
        ssq += __shfl_xor(ssq, 2);
        const float scale = 8.0f / sqrtf(ssq);
        short8 g0, g1;
#pragma unroll
        for (int k = 0; k < 4; ++k) {
            const float a0 = v0[k] * scale, a1 = v1[k] * scale;
            const float a2 = v2[k] * scale, a3 = v3[k] * scale;
            g0[k]     = (short)f2bf(0.5f * a0 * (1.0f + erff(a0 * 0.70710678118654752f)));
            g0[4 + k] = (short)f2bf(0.5f * a1 * (1.0f + erff(a1 * 0.70710678118654752f)));
            g1[k]     = (short)f2bf(0.5f * a2 * (1.0f + erff(a2 * 0.70710678118654752f)));
            g1[4 + k] = (short)f2bf(0.5f * a3 * (1.0f + erff(a3 * 0.70710678118654752f)));
        }
        *(short8*)(sP + r * 128 + (((2 * tq)     ^ (r & 7)) << 4)) = g0;
        *(short8*)(sP + r * 128 + (((2 * tq + 1) ^ (r & 7)) << 4)) = g1;
    }
    __syncthreads();

    // ---- Phase C: y = s' @ Pv (swapped: D[m=d][n=q]); float4 stores ----
    short8 sfr[8][2];
#pragma unroll
    for (int qb = 0; qb < 8; ++qb)
#pragma unroll
        for (int ks = 0; ks < 2; ++ks) {
            const int q = qb * 16 + llo;
            sfr[qb][ks] = *(const short8*)(sP + q * 128 +
                              (((ks * 4 + lhi) ^ (q & 7)) << 4));
        }

    const int d0 = w * 128;
#pragma unroll 2
    for (int dt = 0; dt < 8; ++dt) {
        const unsigned short* ap = PvT + (size_t)(d0 + dt * 16 + llo) * 64 + lhi * 8;
        const short8 pa0 = *(const short8*)ap;
        const short8 pa1 = *(const short8*)(ap + 32);
#pragma unroll
        for (int qb = 0; qb < 8; ++qb) {
            f32x4 c2 = (f32x4){0.f, 0.f, 0.f, 0.f};
            c2 = __builtin_amdgcn_mfma_f32_16x16x32_bf16(pa0, sfr[qb][0], c2, 0, 0, 0);
            c2 = __builtin_amdgcn_mfma_f32_16x16x32_bf16(pa1, sfr[qb][1], c2, 0, 0, 0);
            *(float4v*)(out + (size_t)(R0 + qb * 16 + llo) * DD + d0 + dt * 16 + lhi * 4) = c2;
        }
    }
}

// ---------------------------------------------------------------------------
extern "C" void kernel_launch(void* const* d_in, const int* in_sizes, int n_in,
                              void* d_out, int out_size, void* d_ws, size_t ws_size,
                              hipStream_t stream) {
    (void)in_sizes; (void)n_in; (void)out_size; (void)ws_size;
    const float* x  = (const float*)d_in[0];
    const float* Wq = (const float*)d_in[1];
    const float* Pk = (const float*)d_in[2];
    const float* Pv = (const float*)d_in[3];
    float* out = (float*)d_out;

    // ws layout (256 KB): Kp bf16 [64][1024] @ 0; PvT bf16 [1024][64] @ 128K
    unsigned short* Kp  = (unsigned short*)d_ws;
    unsigned short* PvT = (unsigned short*)((char*)d_ws + 131072);

    kpv_kernel<<<80, 256, 0, stream>>>(Wq, Pk, Pv, Kp, PvT);
    pattn_kernel<<<256, 512, 0, stream>>>(x, Kp, PvT, out);
}